// Round 1
// baseline (800.687 us; speedup 1.0000x reference)
//
#include <hip/hip_runtime.h>
#include <math.h>

#define OUT_G 32
#define NUM_SEG 32768      // 32^3
#define C 128
#define SCAN_THREADS 1024
#define SCAN_PER_T (NUM_SEG / SCAN_THREADS)   // 32

// Pass 1: compute segment id per point, histogram counts per segment.
__global__ void hist_kernel(const int* __restrict__ coords, int* __restrict__ counts,
                            int* __restrict__ seg, int n) {
    int p = blockIdx.x * blockDim.x + threadIdx.x;
    if (p >= n) return;
    int x = coords[3 * p + 0] >> 1;   // coords in [0,64), /2 == >>1
    int y = coords[3 * p + 1] >> 1;
    int z = coords[3 * p + 2] >> 1;
    int s = (x * OUT_G + y) * OUT_G + z;
    seg[p] = s;
    atomicAdd(&counts[s], 1);
}

// Pass 2: exclusive scan of 32768 counts in a single 1024-thread block.
// Writes offsets (pristine starts) and cursors (working copy for scatter).
__global__ void scan_kernel(const int* __restrict__ counts, int* __restrict__ offsets,
                            int* __restrict__ cursors) {
    __shared__ int sums[SCAN_THREADS];
    int t = threadIdx.x;
    int base = t * SCAN_PER_T;
    int local[SCAN_PER_T];
    int run = 0;
#pragma unroll
    for (int j = 0; j < SCAN_PER_T; ++j) { local[j] = run; run += counts[base + j]; }
    sums[t] = run;
    __syncthreads();
    // Hillis-Steele inclusive scan over 1024 partials
    for (int off = 1; off < SCAN_THREADS; off <<= 1) {
        int x = (t >= off) ? sums[t - off] : 0;
        __syncthreads();
        sums[t] += x;
        __syncthreads();
    }
    int ebase = (t == 0) ? 0 : sums[t - 1];
#pragma unroll
    for (int j = 0; j < SCAN_PER_T; ++j) {
        int v = ebase + local[j];
        offsets[base + j] = v;
        cursors[base + j] = v;
    }
}

// Pass 3: scatter point indices grouped by segment.
// After this, cursors[s] == offsets[s] + count[s] (== end offset).
__global__ void scatter_kernel(const int* __restrict__ seg, int* __restrict__ cursors,
                               int* __restrict__ idx, int n) {
    int p = blockIdx.x * blockDim.x + threadIdx.x;
    if (p >= n) return;
    int s = seg[p];
    int pos = atomicAdd(&cursors[s], 1);
    idx[pos] = p;
}

// Pass 4: one block per segment; gather rows, max-reduce, write [S,C] output.
// Thread layout: q = tid&31 -> float4 channel group, r = tid>>5 -> row slot.
// Each iteration reads 4 rows x 512B fully coalesced (16B/lane).
__global__ void __launch_bounds__(128) pool_kernel(
        const float* __restrict__ feats, const int* __restrict__ idx,
        const int* __restrict__ offsets, const int* __restrict__ cursors,
        float* __restrict__ out) {
    int s = blockIdx.x;
    int tid = threadIdx.x;
    int q = tid & 31;
    int r = tid >> 5;
    int start = offsets[s];
    int end = cursors[s];

    float4 m = make_float4(-INFINITY, -INFINITY, -INFINITY, -INFINITY);
    for (int i = start; i < end; i += 4) {
        int row = i + r;
        if (row < end) {
            int p = idx[row];
            const float4 v = *reinterpret_cast<const float4*>(feats + (size_t)p * C + q * 4);
            m.x = fmaxf(m.x, v.x);
            m.y = fmaxf(m.y, v.y);
            m.z = fmaxf(m.z, v.z);
            m.w = fmaxf(m.w, v.w);
        }
    }

    __shared__ float4 red[128];
    red[tid] = m;
    __syncthreads();
    if (tid < 32) {
        float4 a = red[tid], b = red[tid + 32], c = red[tid + 64], d = red[tid + 96];
        float4 res;
        res.x = fmaxf(fmaxf(a.x, b.x), fmaxf(c.x, d.x));
        res.y = fmaxf(fmaxf(a.y, b.y), fmaxf(c.y, d.y));
        res.z = fmaxf(fmaxf(a.z, b.z), fmaxf(c.z, d.z));
        res.w = fmaxf(fmaxf(a.w, b.w), fmaxf(c.w, d.w));
        if (end <= start) res = make_float4(0.f, 0.f, 0.f, 0.f);  // empty voxel -> 0
        reinterpret_cast<float4*>(out)[(size_t)s * (C / 4) + tid] = res;
    }
}

extern "C" void kernel_launch(void* const* d_in, const int* in_sizes, int n_in,
                              void* d_out, int out_size, void* d_ws, size_t ws_size,
                              hipStream_t stream) {
    const float* feats  = (const float*)d_in[0];
    const int*   coords = (const int*)d_in[1];
    float*       out    = (float*)d_out;
    int n = in_sizes[1] / 3;   // 1,000,000 points

    // Workspace layout (ints): counts | offsets | cursors | seg[n] | idx[n]
    int* ws      = (int*)d_ws;
    int* counts  = ws;
    int* offsets = ws + NUM_SEG;
    int* cursors = ws + 2 * NUM_SEG;
    int* seg     = ws + 3 * NUM_SEG;
    int* idx     = seg + n;

    hipMemsetAsync(counts, 0, NUM_SEG * sizeof(int), stream);

    int blk = 256;
    hist_kernel<<<(n + blk - 1) / blk, blk, 0, stream>>>(coords, counts, seg, n);
    scan_kernel<<<1, SCAN_THREADS, 0, stream>>>(counts, offsets, cursors);
    scatter_kernel<<<(n + blk - 1) / blk, blk, 0, stream>>>(seg, cursors, idx, n);
    pool_kernel<<<NUM_SEG, 128, 0, stream>>>(feats, idx, offsets, cursors, out);
}

// Round 3
// 765.692 us; speedup vs baseline: 1.0457x; 1.0457x over previous
//
#include <hip/hip_runtime.h>
#include <math.h>

#define OUT_G 32
#define NUM_SEG 32768      // 32^3
#define C 128
#define SCAN_THREADS 1024
#define SCAN_PER_T (NUM_SEG / SCAN_THREADS)   // 32
#define CHUNK 128          // rows staged to LDS per pool iteration

typedef float vfloat4 __attribute__((ext_vector_type(4)));  // clang vector: ok for nontemporal builtins

// Pass 1: compute segment id per point, histogram counts per segment.
__global__ void hist_kernel(const int* __restrict__ coords, int* __restrict__ counts,
                            int* __restrict__ seg, int n) {
    int p = blockIdx.x * blockDim.x + threadIdx.x;
    if (p >= n) return;
    int x = coords[3 * p + 0] >> 1;   // coords in [0,64), /2 == >>1
    int y = coords[3 * p + 1] >> 1;
    int z = coords[3 * p + 2] >> 1;
    int s = (x * OUT_G + y) * OUT_G + z;
    seg[p] = s;
    atomicAdd(&counts[s], 1);
}

// Pass 2: exclusive scan of 32768 counts in a single 1024-thread block.
__global__ void scan_kernel(const int* __restrict__ counts, int* __restrict__ offsets,
                            int* __restrict__ cursors) {
    __shared__ int sums[SCAN_THREADS];
    int t = threadIdx.x;
    int base = t * SCAN_PER_T;
    int local[SCAN_PER_T];
    int run = 0;
#pragma unroll
    for (int j = 0; j < SCAN_PER_T; ++j) { local[j] = run; run += counts[base + j]; }
    sums[t] = run;
    __syncthreads();
    for (int off = 1; off < SCAN_THREADS; off <<= 1) {
        int x = (t >= off) ? sums[t - off] : 0;
        __syncthreads();
        sums[t] += x;
        __syncthreads();
    }
    int ebase = (t == 0) ? 0 : sums[t - 1];
#pragma unroll
    for (int j = 0; j < SCAN_PER_T; ++j) {
        int v = ebase + local[j];
        offsets[base + j] = v;
        cursors[base + j] = v;
    }
}

// Pass 3: scatter point indices grouped by segment.
// After this, cursors[s] == offsets[s] + count[s] (== end offset).
__global__ void scatter_kernel(const int* __restrict__ seg, int* __restrict__ cursors,
                               int* __restrict__ idx, int n) {
    int p = blockIdx.x * blockDim.x + threadIdx.x;
    if (p >= n) return;
    int s = seg[p];
    int pos = atomicAdd(&cursors[s], 1);
    idx[pos] = p;
}

// Pass 4: one block (256 thr = 8 row-slots x 32 channel-lanes) per segment.
// idx list staged through LDS so the feats gathers have no global->global
// dependency chain: each thread issues all its float4 loads back-to-back.
__global__ void __launch_bounds__(256) pool_kernel(
        const float* __restrict__ feats, const int* __restrict__ idx,
        const int* __restrict__ offsets, const int* __restrict__ cursors,
        float* __restrict__ out) {
    int s = blockIdx.x;
    int tid = threadIdx.x;
    int q = tid & 31;    // float4 channel group
    int r = tid >> 5;    // row slot in [0,8)
    int start = offsets[s];
    int end = cursors[s];

    __shared__ int sidx[CHUNK];
    vfloat4 m = {-INFINITY, -INFINITY, -INFINITY, -INFINITY};

    for (int base = start; base < end; base += CHUNK) {
        int cnt = end - base;
        if (cnt > CHUNK) cnt = CHUNK;
        if (tid < cnt) sidx[tid] = idx[base + tid];
        __syncthreads();
        for (int j = r; j < cnt; j += 8) {
            int p = sidx[j];
            const vfloat4 v = __builtin_nontemporal_load(
                reinterpret_cast<const vfloat4*>(feats + (size_t)p * C) + q);
            m.x = fmaxf(m.x, v.x);
            m.y = fmaxf(m.y, v.y);
            m.z = fmaxf(m.z, v.z);
            m.w = fmaxf(m.w, v.w);
        }
        __syncthreads();
    }

    __shared__ vfloat4 red[256];
    red[tid] = m;
    __syncthreads();
    if (tid < 32) {
        vfloat4 res = red[tid];
#pragma unroll
        for (int k = 1; k < 8; ++k) {
            vfloat4 b = red[tid + 32 * k];
            res.x = fmaxf(res.x, b.x);
            res.y = fmaxf(res.y, b.y);
            res.z = fmaxf(res.z, b.z);
            res.w = fmaxf(res.w, b.w);
        }
        if (end <= start) res = (vfloat4){0.f, 0.f, 0.f, 0.f};  // empty voxel -> 0
        __builtin_nontemporal_store(res, reinterpret_cast<vfloat4*>(out) + (size_t)s * (C / 4) + tid);
    }
}

extern "C" void kernel_launch(void* const* d_in, const int* in_sizes, int n_in,
                              void* d_out, int out_size, void* d_ws, size_t ws_size,
                              hipStream_t stream) {
    const float* feats  = (const float*)d_in[0];
    const int*   coords = (const int*)d_in[1];
    float*       out    = (float*)d_out;
    int n = in_sizes[1] / 3;   // 1,000,000 points

    // Workspace layout (ints): counts | offsets | cursors | seg[n] | idx[n]
    int* ws      = (int*)d_ws;
    int* counts  = ws;
    int* offsets = ws + NUM_SEG;
    int* cursors = ws + 2 * NUM_SEG;
    int* seg     = ws + 3 * NUM_SEG;
    int* idx     = seg + n;

    (void)hipMemsetAsync(counts, 0, NUM_SEG * sizeof(int), stream);

    int blk = 256;
    hist_kernel<<<(n + blk - 1) / blk, blk, 0, stream>>>(coords, counts, seg, n);
    scan_kernel<<<1, SCAN_THREADS, 0, stream>>>(counts, offsets, cursors);
    scatter_kernel<<<(n + blk - 1) / blk, blk, 0, stream>>>(seg, cursors, idx, n);
    pool_kernel<<<NUM_SEG, 256, 0, stream>>>(feats, idx, offsets, cursors, out);
}